// Round 4
// baseline (125.633 us; speedup 1.0000x reference)
//
#include <hip/hip_runtime.h>
#include <hip/hip_cooperative_groups.h>
#include <math.h>
#include <complex>

#define T_STEPS 16384
#define BATCH   512
#define KF      5
#define TAU     (T_STEPS + KF - 1)   /* 16388 */
#define NCHUNK  256
#define CHLEN   (T_STEPS / NCHUNK)   /* 64 */
#define NTAU    (CHLEN + KF - 1)     /* 68 taus per chunk */
#define NSER    6                    /* ||M^5||~5e-9, far under bf16 floor */
#define LSTRIDE 69                   /* 69 % 32 = 5, coprime -> conflict-free */

struct Coefs {
    double b0, b1, b2, b3, b4;   /* FIR numerator */
    double c0, c1, c2, c3;       /* a_rev[:-1] = [a4,a3,a2,a1] */
};
struct Mats {
    double m[NSER - 1][16];      /* M^1..M^5, m[d][j*4+i]: init j -> end i */
};

namespace cg = cooperative_groups;

__global__ __launch_bounds__(512, 2) void k_fused(const float* __restrict__ signal,
                                                  const float* __restrict__ noise,
                                                  const Coefs k,
                                                  const Mats mats,
                                                  double* __restrict__ pend,
                                                  float* __restrict__ out) {
    __shared__ float  nt[BATCH * LSTRIDE];   /* noise tile, [b][j] stride 69: 141,312 B */
    __shared__ double part[NTAU * 8];        /* per-wave mean partials: 4,352 B */
    __shared__ double sd[NTAU];              /* noise sd per tau: 544 B */

    const int tid = threadIdx.x;
    const int b   = tid;
    const int w   = tid >> 6;
    const int l   = tid & 63;
    const int c   = blockIdx.x;
    const int t0  = c * CHLEN;

    /* ---- stage noise tile: rows r (=batch), coalesced along tau ---- */
    for (int rr = 0; rr < 64; ++rr) {
        const int r = w * 64 + rr;
        const float* np = noise + (size_t)r * TAU + t0;
        nt[r * LSTRIDE + l] = np[l];
        if (l < 4) nt[r * LSTRIDE + 64 + l] = np[64 + l];
    }

    /* ---- signal tile into registers (coalesced: consecutive b) ---- */
    float sval[NTAU];
    #pragma unroll
    for (int j = 0; j < NTAU; ++j) {
        const int tau = t0 + j;
        sval[j] = (tau >= 4) ? signal[(size_t)(tau - 4) * BATCH + b] : 0.0f;
    }

    /* ---- per-tau batch mean -> sd (f64 reduce: shfl tree + LDS combine) ---- */
    #pragma unroll
    for (int j = 0; j < NTAU; ++j) {
        double v = (double)sval[j];
        for (int off = 32; off > 0; off >>= 1) v += __shfl_down(v, off, 64);
        if (l == 0) part[j * 8 + w] = v;
    }
    __syncthreads();
    if (tid < NTAU) {
        const double c1 = 2.0 * 1.602176563e-19 * 50000000000.0;
        const double c2 = 4.0 * 1.3806488e-23 * 300.0 * 50000000000.0 / 1000000.0;
        const double DARK = 1e-10;
        double ssum = 0.0;
        #pragma unroll
        for (int i = 0; i < 8; ++i) ssum += part[tid * 8 + i];
        sd[tid] = sqrt(c1 * (ssum / 512.0 + DARK) + c2);
    }
    __syncthreads();

    /* ---- phase 1: FIR + zero-init IIR; s stays in registers ---- */
    auto XN = [&](int j) -> double {
        return sd[j] * (double)nt[b * LSTRIDE + j] + (double)sval[j];
    };

    float sreg[CHLEN];
    double z0 = 0.0, z1 = 0.0, z2 = 0.0, z3 = 0.0;
    {
        double w0 = XN(0), w1 = XN(1), w2 = XN(2), w3 = XN(3), w4;
        #pragma unroll
        for (int i = 0; i < CHLEN; ++i) {
            w4 = XN(i + 4);
            const double s = k.b0 * w0 + k.b1 * w1 + k.b2 * w2 + k.b3 * w3 + k.b4 * w4;
            sreg[i] = (float)s;
            double y;
            if (c == 0 && i < 5) y = s;                   /* passthrough head */
            else y = s - (k.c0 * z0 + k.c1 * z1 + k.c2 * z2 + k.c3 * z3);
            z0 = z1; z1 = z2; z2 = z3; z3 = y;
            w0 = w1; w1 = w2; w2 = w3; w3 = w4;
        }
    }
    pend[(size_t)(c * 4 + 0) * BATCH + b] = z0;
    pend[(size_t)(c * 4 + 1) * BATCH + b] = z1;
    pend[(size_t)(c * 4 + 2) * BATCH + b] = z2;
    pend[(size_t)(c * 4 + 3) * BATCH + b] = z3;

    cg::this_grid().sync();

    /* ---- phase 2: y0 from truncated Neumann series over neighbor pend ---- */
    z0 = 0.0; z1 = 0.0; z2 = 0.0; z3 = 0.0;
    #pragma unroll
    for (int d = 1; d <= NSER; ++d) {
        if (d <= c) {
            const int j = c - d;
            const double p0 = pend[(size_t)(j * 4 + 0) * BATCH + b];
            const double p1 = pend[(size_t)(j * 4 + 1) * BATCH + b];
            const double p2 = pend[(size_t)(j * 4 + 2) * BATCH + b];
            const double p3 = pend[(size_t)(j * 4 + 3) * BATCH + b];
            if (d == 1) {
                z0 += p0; z1 += p1; z2 += p2; z3 += p3;
            } else {
                const double* m = mats.m[d - 2];
                z0 += p0 * m[0]  + p1 * m[4]  + p2 * m[8]  + p3 * m[12];
                z1 += p0 * m[1]  + p1 * m[5]  + p2 * m[9]  + p3 * m[13];
                z2 += p0 * m[2]  + p1 * m[6]  + p2 * m[10] + p3 * m[14];
                z3 += p0 * m[3]  + p1 * m[7]  + p2 * m[11] + p3 * m[15];
            }
        }
    }

    /* ---- replay with correct init; write output ---- */
    #pragma unroll
    for (int i = 0; i < CHLEN; ++i) {
        const double s = (double)sreg[i];
        double y;
        if (c == 0 && i < 5) y = s;
        else y = s - (k.c0 * z0 + k.c1 * z1 + k.c2 * z2 + k.c3 * z3);
        z0 = z1; z1 = z2; z2 = z3; z3 = y;
        out[(size_t)(t0 + i) * BATCH + b] = (float)y;
    }
}

/* ---- host: replicate _butter_lowpass exactly (f64, same algorithm) ---- */
static Coefs make_coefs() {
    const int order = 4;
    const double wn = 25000000000.0 / (0.5 / 1e-12);     /* 0.05 */
    const double warped = 4.0 * tan(M_PI * wn / 2.0);
    std::complex<double> p[4];
    for (int kk = 1; kk <= order; ++kk)
        p[kk - 1] = warped * std::exp(std::complex<double>(0.0,
                        M_PI * (2 * kk + order - 1) / (2.0 * order)));
    const double gain = warped * warped * warped * warped;
    const double fs2 = 4.0;
    std::complex<double> pz[4], prod(1.0, 0.0);
    for (int i = 0; i < 4; ++i) {
        pz[i] = (fs2 + p[i]) / (fs2 - p[i]);
        prod *= (fs2 - p[i]);
    }
    const double gz = gain * std::real(std::complex<double>(1.0, 0.0) / prod);
    std::complex<double> ac[5] = { {1,0}, {0,0}, {0,0}, {0,0}, {0,0} };
    for (int i = 0; i < 4; ++i)
        for (int j = i + 1; j >= 1; --j)
            ac[j] = ac[j] - pz[i] * ac[j - 1];
    Coefs k;
    k.b0 = gz * 1.0; k.b1 = gz * 4.0; k.b2 = gz * 6.0; k.b3 = gz * 4.0; k.b4 = gz * 1.0;
    k.c0 = std::real(ac[4]);
    k.c1 = std::real(ac[3]);
    k.c2 = std::real(ac[2]);
    k.c3 = std::real(ac[1]);
    return k;
}

/* compose(P,Q)[j][i] = sum_k P[j*4+k] * Q[k*4+i] */
static void mat_compose(const double* P, const double* Q, double* R) {
    double t[16];
    for (int j = 0; j < 4; ++j)
        for (int i = 0; i < 4; ++i) {
            double s = 0.0;
            for (int kk = 0; kk < 4; ++kk) s += P[j * 4 + kk] * Q[kk * 4 + i];
            t[j * 4 + i] = s;
        }
    for (int i = 0; i < 16; ++i) R[i] = t[i];
}

static Mats make_mats(const Coefs& k) {
    double S[16] = {0};
    S[1 * 4 + 0] = 1.0;
    S[2 * 4 + 1] = 1.0;
    S[3 * 4 + 2] = 1.0;
    S[0 * 4 + 3] = -k.c0;
    S[1 * 4 + 3] = -k.c1;
    S[2 * 4 + 3] = -k.c2;
    S[3 * 4 + 3] = -k.c3;
    double M[16] = {1,0,0,0, 0,1,0,0, 0,0,1,0, 0,0,0,1};
    for (int i = 0; i < CHLEN; ++i) mat_compose(M, S, M);
    Mats mm;
    for (int i = 0; i < 16; ++i) mm.m[0][i] = M[i];
    for (int d = 1; d < NSER - 1; ++d) mat_compose(mm.m[d - 1], M, mm.m[d]);
    return mm;
}

extern "C" void kernel_launch(void* const* d_in, const int* in_sizes, int n_in,
                              void* d_out, int out_size, void* d_ws, size_t ws_size,
                              hipStream_t stream) {
    const float* signal = (const float*)d_in[0];
    const float* noise  = (const float*)d_in[1];
    float* out = (float*)d_out;

    const Coefs k  = make_coefs();   /* host f64 math; deterministic each call */
    const Mats  mm = make_mats(k);

    double* pend = (double*)d_ws;    /* 256*4*512*8 = 4 MB */

    void* args[] = { (void*)&signal, (void*)&noise, (void*)&k, (void*)&mm,
                     (void*)&pend, (void*)&out };
    hipLaunchCooperativeKernel((const void*)k_fused, dim3(NCHUNK), dim3(512),
                               args, 0, stream);
}

// Round 5
// 64.945 us; speedup vs baseline: 1.9345x; 1.9345x over previous
//
#include <hip/hip_runtime.h>
#include <math.h>
#include <complex>

#define T_STEPS 16384
#define BATCH   512
#define KF      5
#define TAU     (T_STEPS + KF - 1)   /* 16388 */
#define NCHUNK  512
#define CHLEN   (T_STEPS / NCHUNK)   /* 32 */
#define NTAU    (CHLEN + KF - 1)     /* 36 taus per chunk */
#define NSER    12                   /* rho(M)^NSER = 0.148^12 ~ 1e-10 */
#define LSTRIDE (NTAU + 1)           /* 37 % 32 = 5, odd -> 2-way max (free) */

struct Coefs {
    double b0, b1, b2, b3, b4;   /* FIR numerator */
    double c0, c1, c2, c3;       /* a_rev[:-1] = [a4,a3,a2,a1] */
};
struct Mat { double m[16]; };    /* m[j*4+i]: init-state j -> end-state i, M = S^CHLEN */

/* XCD-bijective swizzle (NCHUNK % 8 == 0): consecutive chunks -> same XCD,
   so k_apply's pend[c-1..c-12] reads hit that XCD's L2. */
__device__ __forceinline__ int swz_chunk(int w) { return (w & 7) * (NCHUNK / 8) + (w >> 3); }

/* ---- K A: fused sd + noise-stage + FIR + zero-init IIR ----
   block = chunk (512 of them), thread = batch lane b. */
__global__ __launch_bounds__(512, 4) void k_stage(const float* __restrict__ signal,
                                                  const float* __restrict__ noise,
                                                  const Coefs k,
                                                  float* __restrict__ sbuf,
                                                  double* __restrict__ pend) {
    __shared__ float  nt[BATCH * LSTRIDE];   /* 512*37*4 = 75,776 B -> 2 blocks/CU */
    __shared__ double part[NTAU * 8];
    __shared__ double sd[NTAU];

    const int tid = threadIdx.x;
    const int b   = tid;
    const int w   = tid >> 6;
    const int l   = tid & 63;
    const int c   = swz_chunk(blockIdx.x);
    const int t0  = c * CHLEN;

    /* stage noise tile: wave w covers rows w*64..w*64+63; lanes 0..35 = taus */
    if (l < NTAU) {
        const float* np = noise + (size_t)t0 + l;
        #pragma unroll 8
        for (int rr = 0; rr < 64; ++rr) {
            const int r = (w << 6) + rr;
            nt[r * LSTRIDE + l] = np[(size_t)r * TAU];
        }
    }

    /* signal window into registers (coalesced over b) */
    float sval[NTAU];
    #pragma unroll
    for (int j = 0; j < NTAU; ++j) {
        const int tau = t0 + j;
        sval[j] = (tau >= 4) ? signal[(size_t)(tau - 4) * BATCH + b] : 0.0f;
    }

    /* per-tau batch mean over all 512 b -> sd[] */
    #pragma unroll
    for (int j = 0; j < NTAU; ++j) {
        double v = (double)sval[j];
        for (int off = 32; off > 0; off >>= 1) v += __shfl_down(v, off, 64);
        if (l == 0) part[j * 8 + w] = v;
    }
    __syncthreads();                          /* covers nt staging + part */
    if (tid < NTAU) {
        const double c1 = 2.0 * 1.602176563e-19 * 50000000000.0;
        const double c2 = 4.0 * 1.3806488e-23 * 300.0 * 50000000000.0 / 1000000.0;
        double ssum = 0.0;
        #pragma unroll
        for (int i = 0; i < 8; ++i) ssum += part[tid * 8 + i];
        sd[tid] = sqrt(c1 * (ssum / 512.0 + 1e-10) + c2);
    }
    __syncthreads();

    /* FIR + zero-init IIR; s -> gmem (f32), end state -> pend */
    auto XN = [&](int j) -> double {
        return sd[j] * (double)nt[b * LSTRIDE + j] + (double)sval[j];
    };
    double w0 = XN(0), w1 = XN(1), w2 = XN(2), w3 = XN(3), w4;
    double z0 = 0.0, z1 = 0.0, z2 = 0.0, z3 = 0.0;
    #pragma unroll
    for (int i = 0; i < CHLEN; ++i) {
        w4 = XN(i + 4);
        const double s = k.b0 * w0 + k.b1 * w1 + k.b2 * w2 + k.b3 * w3 + k.b4 * w4;
        sbuf[(size_t)(t0 + i) * BATCH + b] = (float)s;
        const double y = (c == 0 && i < 5) ? s
                       : s - (k.c0 * z0 + k.c1 * z1 + k.c2 * z2 + k.c3 * z3);
        z0 = z1; z1 = z2; z2 = z3; z3 = y;
        w0 = w1; w1 = w2; w2 = w3; w3 = w4;
    }
    pend[(size_t)(c * 4 + 0) * BATCH + b] = z0;
    pend[(size_t)(c * 4 + 1) * BATCH + b] = z1;
    pend[(size_t)(c * 4 + 2) * BATCH + b] = z2;
    pend[(size_t)(c * 4 + 3) * BATCH + b] = z3;
}

/* ---- K B: Horner series init + replay ----
   y0(c) = p(c-1) + M*(p(c-2) + M*(p(c-3) + ...)), truncated at NSER terms. */
__global__ __launch_bounds__(512, 4) void k_apply(const float* __restrict__ sbuf,
                                                  const Coefs k,
                                                  const Mat M,
                                                  const double* __restrict__ pend,
                                                  float* __restrict__ out) {
    const int b  = threadIdx.x;
    const int c  = swz_chunk(blockIdx.x);
    const int t0 = c * CHLEN;

    double z0 = 0.0, z1 = 0.0, z2 = 0.0, z3 = 0.0;
    #pragma unroll
    for (int d = NSER; d >= 1; --d) {
        if (d <= c) {
            const int j = c - d;
            const double p0 = pend[(size_t)(j * 4 + 0) * BATCH + b];
            const double p1 = pend[(size_t)(j * 4 + 1) * BATCH + b];
            const double p2 = pend[(size_t)(j * 4 + 2) * BATCH + b];
            const double p3 = pend[(size_t)(j * 4 + 3) * BATCH + b];
            const double n0 = p0 + M.m[0] * z0 + M.m[4] * z1 + M.m[8]  * z2 + M.m[12] * z3;
            const double n1 = p1 + M.m[1] * z0 + M.m[5] * z1 + M.m[9]  * z2 + M.m[13] * z3;
            const double n2 = p2 + M.m[2] * z0 + M.m[6] * z1 + M.m[10] * z2 + M.m[14] * z3;
            const double n3 = p3 + M.m[3] * z0 + M.m[7] * z1 + M.m[11] * z2 + M.m[15] * z3;
            z0 = n0; z1 = n1; z2 = n2; z3 = n3;
        }
    }

    #pragma unroll
    for (int i = 0; i < CHLEN; ++i) {
        const double s = (double)sbuf[(size_t)(t0 + i) * BATCH + b];
        const double y = (c == 0 && i < 5) ? s
                       : s - (k.c0 * z0 + k.c1 * z1 + k.c2 * z2 + k.c3 * z3);
        z0 = z1; z1 = z2; z2 = z3; z3 = y;
        out[(size_t)(t0 + i) * BATCH + b] = (float)y;
    }
}

/* ---- host: replicate _butter_lowpass exactly (f64, same algorithm) ---- */
static Coefs make_coefs() {
    const int order = 4;
    const double wn = 25000000000.0 / (0.5 / 1e-12);     /* 0.05 */
    const double warped = 4.0 * tan(M_PI * wn / 2.0);
    std::complex<double> p[4];
    for (int kk = 1; kk <= order; ++kk)
        p[kk - 1] = warped * std::exp(std::complex<double>(0.0,
                        M_PI * (2 * kk + order - 1) / (2.0 * order)));
    const double gain = warped * warped * warped * warped;
    const double fs2 = 4.0;
    std::complex<double> pz[4], prod(1.0, 0.0);
    for (int i = 0; i < 4; ++i) {
        pz[i] = (fs2 + p[i]) / (fs2 - p[i]);
        prod *= (fs2 - p[i]);
    }
    const double gz = gain * std::real(std::complex<double>(1.0, 0.0) / prod);
    std::complex<double> ac[5] = { {1,0}, {0,0}, {0,0}, {0,0}, {0,0} };
    for (int i = 0; i < 4; ++i)
        for (int j = i + 1; j >= 1; --j)
            ac[j] = ac[j] - pz[i] * ac[j - 1];
    Coefs k;
    k.b0 = gz * 1.0; k.b1 = gz * 4.0; k.b2 = gz * 6.0; k.b3 = gz * 4.0; k.b4 = gz * 1.0;
    k.c0 = std::real(ac[4]);
    k.c1 = std::real(ac[3]);
    k.c2 = std::real(ac[2]);
    k.c3 = std::real(ac[1]);
    return k;
}

/* compose(P,Q)[j][i] = sum_k P[j*4+k] * Q[k*4+i]  ("apply P then Q") */
static void mat_compose(const double* P, const double* Q, double* R) {
    double t[16];
    for (int j = 0; j < 4; ++j)
        for (int i = 0; i < 4; ++i) {
            double s = 0.0;
            for (int kk = 0; kk < 4; ++kk) s += P[j * 4 + kk] * Q[kk * 4 + i];
            t[j * 4 + i] = s;
        }
    for (int i = 0; i < 16; ++i) R[i] = t[i];
}

static Mat make_M(const Coefs& k) {
    double S[16] = {0};
    S[1 * 4 + 0] = 1.0;
    S[2 * 4 + 1] = 1.0;
    S[3 * 4 + 2] = 1.0;
    S[0 * 4 + 3] = -k.c0;
    S[1 * 4 + 3] = -k.c1;
    S[2 * 4 + 3] = -k.c2;
    S[3 * 4 + 3] = -k.c3;
    Mat M;
    double I[16] = {1,0,0,0, 0,1,0,0, 0,0,1,0, 0,0,0,1};
    for (int i = 0; i < 16; ++i) M.m[i] = I[i];
    for (int i = 0; i < CHLEN; ++i) mat_compose(M.m, S, M.m);
    return M;
}

extern "C" void kernel_launch(void* const* d_in, const int* in_sizes, int n_in,
                              void* d_out, int out_size, void* d_ws, size_t ws_size,
                              hipStream_t stream) {
    const float* signal = (const float*)d_in[0];
    const float* noise  = (const float*)d_in[1];
    float* out = (float*)d_out;

    const Coefs k = make_coefs();    /* host f64 math; deterministic each call */
    const Mat   M = make_M(k);

    char* ws = (char*)d_ws;
    float*  sbuf = (float*)ws;                     /* 16384*512*4 = 33,554,432 */
    double* pend = (double*)(ws + 33554432);       /* 512*4*512*8 = 8,388,608  */

    hipLaunchKernelGGL(k_stage, dim3(NCHUNK), dim3(512), 0, stream,
                       signal, noise, k, sbuf, pend);
    hipLaunchKernelGGL(k_apply, dim3(NCHUNK), dim3(512), 0, stream,
                       sbuf, k, M, pend, out);
}

// Round 6
// 46.622 us; speedup vs baseline: 2.6947x; 1.3930x over previous
//
#include <hip/hip_runtime.h>
#include <math.h>
#include <complex>

#define T_STEPS 16384
#define BATCH   512
#define KF      5
#define TAU     (T_STEPS + KF - 1)   /* 16388 */
#define NCHUNK  512
#define CHLEN   (T_STEPS / NCHUNK)   /* 32 */
#define NTAU    (CHLEN + KF - 1)     /* 36 taus per chunk = 9 float4 */
#define NSER    12                   /* rho(M)^NSER = 0.148^12 ~ 1e-10 */

struct Coefs {
    double b0, b1, b2, b3, b4;   /* FIR numerator */
    double c0, c1, c2, c3;       /* a_rev[:-1] = [a4,a3,a2,a1] */
};
struct Mat { double m[16]; };    /* m[j*4+i]: init-state j -> end-state i, M = S^CHLEN */

/* XCD-bijective swizzle (NCHUNK % 8 == 0): runs of 64 consecutive chunks share
   an XCD, so k_apply's pend[c-1..c-12] reads are L2-local. */
__device__ __forceinline__ int swz_chunk(int w) { return (w & 7) * (NCHUNK / 8) + (w >> 3); }

/* ---- K A: sd + FIR + zero-init IIR, all state in registers ----
   block = chunk, thread = batch lane b. noise[b][t0..t0+35] is contiguous
   per thread -> 9 float4 loads, no LDS staging, no transpose. */
__global__ __launch_bounds__(512, 4) void k_stage(const float* __restrict__ signal,
                                                  const float* __restrict__ noise,
                                                  const Coefs k,
                                                  float* __restrict__ sbuf,
                                                  double* __restrict__ pend) {
    __shared__ float  part[NTAU * 8];
    __shared__ double sdsh[NTAU];

    const int tid = threadIdx.x;
    const int b   = tid;
    const int w   = tid >> 6;
    const int l   = tid & 63;
    const int c   = swz_chunk(blockIdx.x);
    const int t0  = c * CHLEN;

    /* noise window -> registers (16B-aligned: b*TAU and t0 both %4==0) */
    const float4* nb = (const float4*)(noise + (size_t)b * TAU + t0);
    float4 nr[9];
    #pragma unroll
    for (int q = 0; q < 9; ++q) nr[q] = nb[q];
    float nv[NTAU];
    #pragma unroll
    for (int q = 0; q < 9; ++q) {
        nv[4 * q + 0] = nr[q].x; nv[4 * q + 1] = nr[q].y;
        nv[4 * q + 2] = nr[q].z; nv[4 * q + 3] = nr[q].w;
    }

    /* signal window (coalesced over b) */
    float sval[NTAU];
    #pragma unroll
    for (int j = 0; j < NTAU; ++j) {
        const int tau = t0 + j;
        sval[j] = (c == 0 && tau < 4) ? 0.0f : signal[(size_t)(tau - 4) * BATCH + b];
    }

    /* per-tau batch mean: f32 wave tree + f64 combine (error ~1e-9 abs in sd) */
    #pragma unroll
    for (int j = 0; j < NTAU; ++j) {
        float v = sval[j];
        for (int off = 32; off > 0; off >>= 1) v += __shfl_down(v, off, 64);
        if (l == 0) part[j * 8 + w] = v;
    }
    __syncthreads();
    if (tid < NTAU) {
        const double c1 = 2.0 * 1.602176563e-19 * 50000000000.0;
        const double c2 = 4.0 * 1.3806488e-23 * 300.0 * 50000000000.0 / 1000000.0;
        double ssum = 0.0;
        #pragma unroll
        for (int i = 0; i < 8; ++i) ssum += (double)part[tid * 8 + i];
        sdsh[tid] = sqrt(c1 * (ssum / 512.0 + 1e-10) + c2);
    }
    __syncthreads();

    /* FIR + zero-init IIR; indices all compile-time (full unroll) */
    auto XN = [&](int j) -> double {
        return sdsh[j] * (double)nv[j] + (double)sval[j];
    };
    double w0 = XN(0), w1 = XN(1), w2 = XN(2), w3 = XN(3), w4;
    double z0 = 0.0, z1 = 0.0, z2 = 0.0, z3 = 0.0;
    #pragma unroll
    for (int i = 0; i < CHLEN; ++i) {
        w4 = XN(i + 4);
        const double s = k.b0 * w0 + k.b1 * w1 + k.b2 * w2 + k.b3 * w3 + k.b4 * w4;
        sbuf[(size_t)(t0 + i) * BATCH + b] = (float)s;
        const double y = (c == 0 && i < 5) ? s
                       : s - (k.c0 * z0 + k.c1 * z1 + k.c2 * z2 + k.c3 * z3);
        z0 = z1; z1 = z2; z2 = z3; z3 = y;
        w0 = w1; w1 = w2; w2 = w3; w3 = w4;
    }
    pend[(size_t)(c * 4 + 0) * BATCH + b] = z0;
    pend[(size_t)(c * 4 + 1) * BATCH + b] = z1;
    pend[(size_t)(c * 4 + 2) * BATCH + b] = z2;
    pend[(size_t)(c * 4 + 3) * BATCH + b] = z3;
}

/* ---- K B: Horner series init + replay; 256-thread blocks, grid (NCHUNK,2) ---- */
__global__ __launch_bounds__(256) void k_apply(const float* __restrict__ sbuf,
                                               const Coefs k,
                                               const Mat M,
                                               const double* __restrict__ pend,
                                               float* __restrict__ out) {
    const int b  = (int)blockIdx.y * 256 + threadIdx.x;
    const int c  = swz_chunk(blockIdx.x);
    const int t0 = c * CHLEN;

    double z0 = 0.0, z1 = 0.0, z2 = 0.0, z3 = 0.0;
    #pragma unroll
    for (int d = NSER; d >= 1; --d) {
        if (d <= c) {
            const int j = c - d;
            const double p0 = pend[(size_t)(j * 4 + 0) * BATCH + b];
            const double p1 = pend[(size_t)(j * 4 + 1) * BATCH + b];
            const double p2 = pend[(size_t)(j * 4 + 2) * BATCH + b];
            const double p3 = pend[(size_t)(j * 4 + 3) * BATCH + b];
            const double n0 = p0 + M.m[0] * z0 + M.m[4] * z1 + M.m[8]  * z2 + M.m[12] * z3;
            const double n1 = p1 + M.m[1] * z0 + M.m[5] * z1 + M.m[9]  * z2 + M.m[13] * z3;
            const double n2 = p2 + M.m[2] * z0 + M.m[6] * z1 + M.m[10] * z2 + M.m[14] * z3;
            const double n3 = p3 + M.m[3] * z0 + M.m[7] * z1 + M.m[11] * z2 + M.m[15] * z3;
            z0 = n0; z1 = n1; z2 = n2; z3 = n3;
        }
    }

    #pragma unroll
    for (int i = 0; i < CHLEN; ++i) {
        const double s = (double)sbuf[(size_t)(t0 + i) * BATCH + b];
        const double y = (c == 0 && i < 5) ? s
                       : s - (k.c0 * z0 + k.c1 * z1 + k.c2 * z2 + k.c3 * z3);
        z0 = z1; z1 = z2; z2 = z3; z3 = y;
        out[(size_t)(t0 + i) * BATCH + b] = (float)y;
    }
}

/* ---- host: replicate _butter_lowpass exactly (f64, same algorithm) ---- */
static Coefs make_coefs() {
    const int order = 4;
    const double wn = 25000000000.0 / (0.5 / 1e-12);     /* 0.05 */
    const double warped = 4.0 * tan(M_PI * wn / 2.0);
    std::complex<double> p[4];
    for (int kk = 1; kk <= order; ++kk)
        p[kk - 1] = warped * std::exp(std::complex<double>(0.0,
                        M_PI * (2 * kk + order - 1) / (2.0 * order)));
    const double gain = warped * warped * warped * warped;
    const double fs2 = 4.0;
    std::complex<double> pz[4], prod(1.0, 0.0);
    for (int i = 0; i < 4; ++i) {
        pz[i] = (fs2 + p[i]) / (fs2 - p[i]);
        prod *= (fs2 - p[i]);
    }
    const double gz = gain * std::real(std::complex<double>(1.0, 0.0) / prod);
    std::complex<double> ac[5] = { {1,0}, {0,0}, {0,0}, {0,0}, {0,0} };
    for (int i = 0; i < 4; ++i)
        for (int j = i + 1; j >= 1; --j)
            ac[j] = ac[j] - pz[i] * ac[j - 1];
    Coefs k;
    k.b0 = gz * 1.0; k.b1 = gz * 4.0; k.b2 = gz * 6.0; k.b3 = gz * 4.0; k.b4 = gz * 1.0;
    k.c0 = std::real(ac[4]);
    k.c1 = std::real(ac[3]);
    k.c2 = std::real(ac[2]);
    k.c3 = std::real(ac[1]);
    return k;
}

/* compose(P,Q)[j][i] = sum_k P[j*4+k] * Q[k*4+i]  ("apply P then Q") */
static void mat_compose(const double* P, const double* Q, double* R) {
    double t[16];
    for (int j = 0; j < 4; ++j)
        for (int i = 0; i < 4; ++i) {
            double s = 0.0;
            for (int kk = 0; kk < 4; ++kk) s += P[j * 4 + kk] * Q[kk * 4 + i];
            t[j * 4 + i] = s;
        }
    for (int i = 0; i < 16; ++i) R[i] = t[i];
}

static Mat make_M(const Coefs& k) {
    double S[16] = {0};
    S[1 * 4 + 0] = 1.0;
    S[2 * 4 + 1] = 1.0;
    S[3 * 4 + 2] = 1.0;
    S[0 * 4 + 3] = -k.c0;
    S[1 * 4 + 3] = -k.c1;
    S[2 * 4 + 3] = -k.c2;
    S[3 * 4 + 3] = -k.c3;
    Mat M;
    double I[16] = {1,0,0,0, 0,1,0,0, 0,0,1,0, 0,0,0,1};
    for (int i = 0; i < 16; ++i) M.m[i] = I[i];
    for (int i = 0; i < CHLEN; ++i) mat_compose(M.m, S, M.m);
    return M;
}

extern "C" void kernel_launch(void* const* d_in, const int* in_sizes, int n_in,
                              void* d_out, int out_size, void* d_ws, size_t ws_size,
                              hipStream_t stream) {
    const float* signal = (const float*)d_in[0];
    const float* noise  = (const float*)d_in[1];
    float* out = (float*)d_out;

    const Coefs k = make_coefs();    /* host f64 math; deterministic each call */
    const Mat   M = make_M(k);

    char* ws = (char*)d_ws;
    float*  sbuf = (float*)ws;                     /* 16384*512*4 = 33,554,432 */
    double* pend = (double*)(ws + 33554432);       /* 512*4*512*8 = 8,388,608  */

    hipLaunchKernelGGL(k_stage, dim3(NCHUNK), dim3(512), 0, stream,
                       signal, noise, k, sbuf, pend);
    hipLaunchKernelGGL(k_apply, dim3(NCHUNK, 2), dim3(256), 0, stream,
                       sbuf, k, M, pend, out);
}